// Round 4
// baseline (414.094 us; speedup 1.0000x reference)
//
#include <hip/hip_runtime.h>

typedef unsigned short u16;
typedef unsigned int u32;
typedef __bf16 bf16x8 __attribute__((ext_vector_type(8)));
typedef float f32x4 __attribute__((ext_vector_type(4)));

#define DEV static __device__ __forceinline__

// async global->LDS, 16B per lane; dest is wave-uniform base + lane*16
DEV void gload16(const void* g, void* l) {
    __builtin_amdgcn_global_load_lds(
        (const __attribute__((address_space(1))) void*)g,
        (__attribute__((address_space(3))) void*)l, 16, 0, 0);
}

DEV void store_c(float* p, float v) { *p = v; }
DEV void store_c(u16* p, float v) { *(__bf16*)p = (__bf16)v; }

// swizzled LDS byte offset: row stride 128B, XOR chunk bits with (row&7)
DEV int swz(int row, int bytecol) { return row * 128 + (bytecol ^ ((row & 7) << 4)); }

// ---------------------------------------------------------------------------
// pack zc = concat(z, connection) as bf16  [8192 x 2048]
// ---------------------------------------------------------------------------
__global__ void pack_zc(const float* __restrict__ z, const float* __restrict__ cn,
                        u16* __restrict__ zc) {
    size_t i = ((size_t)blockIdx.x * blockDim.x + threadIdx.x) * 4;
    size_t t = i >> 11;            // token
    int c = (int)(i & 2047);
    const float* src = (c < 1024) ? (z + t * 1024 + c) : (cn + t * 1024 + (c - 1024));
    float4 v = *reinterpret_cast<const float4*>(src);
    union { __bf16 h[4]; uint2 u; } o;
    o.h[0] = (__bf16)v.x; o.h[1] = (__bf16)v.y;
    o.h[2] = (__bf16)v.z; o.h[3] = (__bf16)v.w;
    *reinterpret_cast<uint2*>(zc + i) = o.u;
}

// ---------------------------------------------------------------------------
// W [K x N] fp32  ->  WT [N x K] bf16
// ---------------------------------------------------------------------------
__global__ void transpose_conv_w(const float* __restrict__ W, u16* __restrict__ WT,
                                 int K, int N) {
    __shared__ float tile[32][33];
    int n0 = blockIdx.x * 32, k0 = blockIdx.y * 32;
    int tx = threadIdx.x, ty = threadIdx.y;
    #pragma unroll
    for (int i = ty; i < 32; i += 8)
        tile[i][tx] = W[(size_t)(k0 + i) * N + n0 + tx];
    __syncthreads();
    #pragma unroll
    for (int i = ty; i < 32; i += 8)
        *(__bf16*)&WT[(size_t)(n0 + i) * K + k0 + tx] = (__bf16)tile[tx][i];
}

// ---------------------------------------------------------------------------
// Vflat [8192 x 1024] bf16 -> Vt [64(bh)][64(hd)][2048(L)] bf16
// ---------------------------------------------------------------------------
__global__ void transpose_v(const u16* __restrict__ Vf, u16* __restrict__ Vt) {
    __shared__ u16 tile[32][33];
    int bh = blockIdx.z; int b = bh >> 4, h = bh & 15;
    int l0 = blockIdx.x * 32, d0 = blockIdx.y * 32;
    int tx = threadIdx.x, ty = threadIdx.y;
    #pragma unroll
    for (int i = ty; i < 32; i += 8)
        tile[i][tx] = Vf[(size_t)(b * 2048 + l0 + i) * 1024 + h * 64 + d0 + tx];
    __syncthreads();
    #pragma unroll
    for (int i = ty; i < 32; i += 8)
        Vt[((size_t)bh * 64 + d0 + i) * 2048 + l0 + tx] = tile[tx][i];
}

// ---------------------------------------------------------------------------
// C[M x N] = A[M x K] @ BT[N x K]^T   (bf16 in, OutT out)
// 128x128 tile, BK=64, 4 waves, global_load_lds staging with pre-swizzled
// source (LDS[row][c] = global[row][c ^ (row&7)]), mfma_f32_16x16x32_bf16.
// ---------------------------------------------------------------------------
template <typename OutT>
__global__ __launch_bounds__(256, 2)
void gemm_bt(const u16* __restrict__ A, const u16* __restrict__ BT,
             OutT* __restrict__ C, int M, int N, int K,
             int lda, int ldb, int ldc) {
    __shared__ u16 As[128 * 64];
    __shared__ u16 Bs[128 * 64];
    const int tid = threadIdx.x;
    const int lane = tid & 63;
    const int wid = tid >> 6;
    const int m0 = blockIdx.x * 128;
    const int n0 = blockIdx.y * 128;
    const int wr = (wid >> 1) * 64;
    const int wc = (wid & 1) * 64;

    f32x4 acc[4][4];
    #pragma unroll
    for (int i = 0; i < 4; ++i)
        #pragma unroll
        for (int j = 0; j < 4; ++j)
            acc[i][j] = f32x4{0.f, 0.f, 0.f, 0.f};

    // staging geometry: slot = (wid*4+p)*64 + lane; row = slot>>3 = wid*32+p*8+(lane>>3)
    // row&7 == lane>>3, so source chunk = (lane&7) ^ (lane>>3) — lane constant.
    const int srcoff = ((lane & 7) ^ (lane >> 3)) * 8;   // elements
    const int rb = wid * 32 + (lane >> 3);
    const u16* aptr[4]; const u16* bptr[4];
    #pragma unroll
    for (int p = 0; p < 4; ++p) {
        aptr[p] = A  + (size_t)(m0 + rb + p * 8) * lda + srcoff;
        bptr[p] = BT + (size_t)(n0 + rb + p * 8) * ldb + srcoff;
    }

    for (int k0 = 0; k0 < K; k0 += 64) {
        __syncthreads();   // previous compute done before overwrite
        #pragma unroll
        for (int p = 0; p < 4; ++p)
            gload16(aptr[p] + k0, (char*)As + (wid * 4 + p) * 1024);
        #pragma unroll
        for (int p = 0; p < 4; ++p)
            gload16(bptr[p] + k0, (char*)Bs + (wid * 4 + p) * 1024);
        __syncthreads();   // staging complete (compiler drains vmcnt before barrier)

        #pragma unroll
        for (int kk = 0; kk < 64; kk += 32) {
            bf16x8 af[4], bfr[4];
            #pragma unroll
            for (int i = 0; i < 4; ++i) {
                int row = wr + i * 16 + (lane & 15);
                af[i] = *reinterpret_cast<const bf16x8*>(
                    reinterpret_cast<const char*>(As) + swz(row, (kk + (lane >> 4) * 8) * 2));
            }
            #pragma unroll
            for (int j = 0; j < 4; ++j) {
                int row = wc + j * 16 + (lane & 15);
                bfr[j] = *reinterpret_cast<const bf16x8*>(
                    reinterpret_cast<const char*>(Bs) + swz(row, (kk + (lane >> 4) * 8) * 2));
            }
            #pragma unroll
            for (int i = 0; i < 4; ++i)
                #pragma unroll
                for (int j = 0; j < 4; ++j)
                    acc[i][j] = __builtin_amdgcn_mfma_f32_16x16x32_bf16(af[i], bfr[j], acc[i][j], 0, 0, 0);
        }
    }

    #pragma unroll
    for (int i = 0; i < 4; ++i)
        #pragma unroll
        for (int j = 0; j < 4; ++j)
            #pragma unroll
            for (int r = 0; r < 4; ++r) {
                int row = m0 + wr + i * 16 + (lane >> 4) * 4 + r;
                int col = n0 + wc + j * 16 + (lane & 15);
                store_c(&C[(size_t)row * ldc + col], acc[i][j][r]);
            }
}

// ---------------------------------------------------------------------------
// Sigmoid attention: out[b,h,q,:] = (sigma(QK^T*scale) @ V) / max(rowsum,1)
// QKf [8192 x 2048]: cols 0-1023 Q, 1024-2047 K.
// grid (L/128, B*H), 4 waves; each wave owns 32 q-rows (2 subtiles of 16).
// SWAPPED QK^T: S = mfma(A=K, B=Q) -> D[key][q], so each lane holds 4
// consecutive keys for one q -> P stored row-major [q][key] with one packed
// ds_write_b64 per (q-subtile, key-subtile); PV A-frag reads stay b128.
// rsum via MFMA against all-ones B (same C row mapping as oacc).
// ---------------------------------------------------------------------------
__global__ __launch_bounds__(256, 2)
void attn_kernel(const u16* __restrict__ QKf, const u16* __restrict__ Vt,
                 u16* __restrict__ Oa, const float* __restrict__ temp) {
    constexpr int L = 2048, D = 1024, QKLD = 2048, HD = 64;
    __shared__ u16 Qs[128 * 64];
    __shared__ u16 Ks[64 * 64];
    __shared__ u16 Vs[64 * 64];
    __shared__ u16 Ps[4][32 * 64];   // per-wave P tile [32 q][64 keys]

    const int tid = threadIdx.x;
    const int lane = tid & 63;
    const int wid = tid >> 6;
    const int bh = blockIdx.y;
    const int b = bh >> 4, h = bh & 15;
    const int q0 = blockIdx.x * 128;
    const float sneg = -temp[0] * 0.125f * 1.44269504f;   // exp2-domain scale

    const u16* Qbase = QKf + (size_t)(b * L) * QKLD + h * HD;
    const u16* Kbase = Qbase + 1024;
    const u16* Vbase = Vt + (size_t)bh * HD * L;

    // staging geometry: one gload16 covers 8 LDS rows; row&7 == lane>>3,
    // so pre-swizzled source chunk = (lane&7) ^ (lane>>3) — lane constant.
    const int srcoff = ((lane & 7) ^ (lane >> 3)) * 8;

    // stage Q once: wave wid covers rows wid*32 .. wid*32+31 (4 gloads)
    #pragma unroll
    for (int p = 0; p < 4; ++p)
        gload16(Qbase + (size_t)(q0 + wid * 32 + p * 8 + (lane >> 3)) * QKLD + srcoff,
                (char*)Qs + (wid * 4 + p) * 1024);

    const int rb = wid * 16 + (lane >> 3);
    const u16* kptr[2]; const u16* vptr[2];
    #pragma unroll
    for (int p = 0; p < 2; ++p) {
        kptr[p] = Kbase + (size_t)(rb + p * 8) * QKLD + srcoff;
        vptr[p] = Vbase + (size_t)(rb + p * 8) * L + srcoff;
    }

    bf16x8 onesf;
    #pragma unroll
    for (int j = 0; j < 8; ++j) onesf[j] = (__bf16)1.0f;

    f32x4 oacc[4][2];
    #pragma unroll
    for (int ct = 0; ct < 4; ++ct)
        #pragma unroll
        for (int i = 0; i < 2; ++i) oacc[ct][i] = f32x4{0.f, 0.f, 0.f, 0.f};
    f32x4 racc[2];
    racc[0] = f32x4{0.f, 0.f, 0.f, 0.f};
    racc[1] = f32x4{0.f, 0.f, 0.f, 0.f};

    for (int k0 = 0; k0 < L; k0 += 64) {
        __syncthreads();   // prev iter done with Ks/Vs
        #pragma unroll
        for (int p = 0; p < 2; ++p)
            gload16(kptr[p] + (size_t)k0 * QKLD, (char*)Ks + (wid * 2 + p) * 1024);
        #pragma unroll
        for (int p = 0; p < 2; ++p)
            gload16(vptr[p] + k0, (char*)Vs + (wid * 2 + p) * 1024);
        __syncthreads();   // staging complete (incl. Q on first iter)

        // S[key][q] = mfma(A=K, B=Q): lane holds q=lane&15 (per subtile),
        // keys = ct*16 + (lane>>4)*4 + r
        f32x4 s[4][2];
        #pragma unroll
        for (int ct = 0; ct < 4; ++ct)
            #pragma unroll
            for (int i = 0; i < 2; ++i) s[ct][i] = f32x4{0.f, 0.f, 0.f, 0.f};
        #pragma unroll
        for (int kk = 0; kk < 64; kk += 32) {
            bf16x8 ak[4], bq[2];
            #pragma unroll
            for (int ct = 0; ct < 4; ++ct) {
                int krow = ct * 16 + (lane & 15);
                ak[ct] = *reinterpret_cast<const bf16x8*>(
                    reinterpret_cast<const char*>(Ks) + swz(krow, (kk + (lane >> 4) * 8) * 2));
            }
            #pragma unroll
            for (int i = 0; i < 2; ++i) {
                int qrow = wid * 32 + i * 16 + (lane & 15);
                bq[i] = *reinterpret_cast<const bf16x8*>(
                    reinterpret_cast<const char*>(Qs) + swz(qrow, (kk + (lane >> 4) * 8) * 2));
            }
            #pragma unroll
            for (int ct = 0; ct < 4; ++ct)
                #pragma unroll
                for (int i = 0; i < 2; ++i)
                    s[ct][i] = __builtin_amdgcn_mfma_f32_16x16x32_bf16(ak[ct], bq[i], s[ct][i], 0, 0, 0);
        }

        // sigmoid -> packed b64 P-store: row = q (i*16 + lane&15),
        // cols ct*16 + (lane>>4)*4 + 0..3 — 4 consecutive keys, one 8B write
        #pragma unroll
        for (int i = 0; i < 2; ++i) {
            int prow = i * 16 + (lane & 15);
            #pragma unroll
            for (int ct = 0; ct < 4; ++ct) {
                union { __bf16 hh[4]; uint2 uu; } pk;
                #pragma unroll
                for (int r = 0; r < 4; ++r)
                    pk.hh[r] = (__bf16)__builtin_amdgcn_rcpf(1.0f + exp2f(s[ct][i][r] * sneg));
                *reinterpret_cast<uint2*>(reinterpret_cast<char*>(Ps[wid]) +
                    swz(prow, ct * 32 + (lane >> 4) * 8)) = pk.uu;
            }
        }
        // no barrier: Ps is per-wave (same-wave DS ops are in-order)

        // O += P @ V ; rsum += P @ ones (matrix pipe)
        #pragma unroll
        for (int kk = 0; kk < 64; kk += 32) {
            bf16x8 ap[2];
            #pragma unroll
            for (int i = 0; i < 2; ++i) {
                int prow = i * 16 + (lane & 15);
                ap[i] = *reinterpret_cast<const bf16x8*>(
                    reinterpret_cast<const char*>(Ps[wid]) + swz(prow, (kk + (lane >> 4) * 8) * 2));
            }
            racc[0] = __builtin_amdgcn_mfma_f32_16x16x32_bf16(ap[0], onesf, racc[0], 0, 0, 0);
            racc[1] = __builtin_amdgcn_mfma_f32_16x16x32_bf16(ap[1], onesf, racc[1], 0, 0, 0);
            #pragma unroll
            for (int ct = 0; ct < 4; ++ct) {
                int vrow = ct * 16 + (lane & 15);   // output channel c
                bf16x8 bv = *reinterpret_cast<const bf16x8*>(
                    reinterpret_cast<const char*>(Vs) + swz(vrow, (kk + (lane >> 4) * 8) * 2));
                #pragma unroll
                for (int i = 0; i < 2; ++i)
                    oacc[ct][i] = __builtin_amdgcn_mfma_f32_16x16x32_bf16(ap[i], bv, oacc[ct][i], 0, 0, 0);
            }
        }
    }

    float rdiv[2][4];
    #pragma unroll
    for (int i = 0; i < 2; ++i)
        #pragma unroll
        for (int r = 0; r < 4; ++r)
            rdiv[i][r] = __builtin_amdgcn_rcpf(fmaxf(racc[i][r], 1.0f));

    #pragma unroll
    for (int ct = 0; ct < 4; ++ct)
        #pragma unroll
        for (int i = 0; i < 2; ++i)
            #pragma unroll
            for (int r = 0; r < 4; ++r) {
                int row = q0 + wid * 32 + i * 16 + (lane >> 4) * 4 + r;
                int col = h * HD + ct * 16 + (lane & 15);
                *(__bf16*)&Oa[(size_t)(b * L + row) * D + col] =
                    (__bf16)(oacc[ct][i][r] * rdiv[i][r]);
            }
}

// ---------------------------------------------------------------------------
extern "C" void kernel_launch(void* const* d_in, const int* in_sizes, int n_in,
                              void* d_out, int out_size, void* d_ws, size_t ws_size,
                              hipStream_t stream) {
    const float* z    = (const float*)d_in[0];
    const float* cn   = (const float*)d_in[1];
    const float* Wq   = (const float*)d_in[2];
    const float* Wk   = (const float*)d_in[3];
    const float* Wv   = (const float*)d_in[4];
    const float* Wo   = (const float*)d_in[5];
    const float* temp = (const float*)d_in[6];

    // Workspace layout (92 MB total):
    //   WqT/WkT contiguous (merged QK GEMM reads them as one [2048][2048] BT).
    //   zc dead after projections -> Vt aliases zc.
    //   Vf dead after transpose_v -> Oa aliases Vf.
    char* ws = (char*)d_ws;
    u16* zc  = (u16*)ws; ws += (size_t)8192 * 2048 * 2;   // 32 MB
    u16* WqT = (u16*)ws; ws += (size_t)1024 * 2048 * 2;   //  4 MB
    u16* WkT = (u16*)ws; ws += (size_t)1024 * 2048 * 2;   //  4 MB (contiguous after WqT)
    u16* WvT = (u16*)ws; ws += (size_t)1024 * 1024 * 2;   //  2 MB
    u16* WoT = (u16*)ws; ws += (size_t)1024 * 1024 * 2;   //  2 MB
    u16* QKf = (u16*)ws; ws += (size_t)8192 * 2048 * 2;   // 32 MB (Q cols 0-1023, K cols 1024-2047)
    u16* Vf  = (u16*)ws; ws += (size_t)8192 * 1024 * 2;   // 16 MB
    u16* Vt  = zc;   // alias: zc dead after projections
    u16* Oa  = Vf;   // alias: Vf dead after transpose_v

    pack_zc<<<16384, 256, 0, stream>>>(z, cn, zc);

    dim3 tb(32, 8);
    transpose_conv_w<<<dim3(32, 64), tb, 0, stream>>>(Wq, WqT, 2048, 1024);
    transpose_conv_w<<<dim3(32, 64), tb, 0, stream>>>(Wk, WkT, 2048, 1024);
    transpose_conv_w<<<dim3(32, 32), tb, 0, stream>>>(Wv, WvT, 1024, 1024);
    transpose_conv_w<<<dim3(32, 32), tb, 0, stream>>>(Wo, WoT, 1024, 1024);

    // merged Q+K projection: [8192,2048] @ [2048,2048]^T -> QKf
    gemm_bt<u16><<<dim3(64, 16), 256, 0, stream>>>(zc, WqT, QKf, 8192, 2048, 2048, 2048, 2048, 2048);
    gemm_bt<u16><<<dim3(64, 8),  256, 0, stream>>>(zc, WvT, Vf,  8192, 1024, 1024, 2048, 1024, 1024);

    transpose_v<<<dim3(64, 2, 64), tb, 0, stream>>>(Vf, Vt);

    attn_kernel<<<dim3(16, 64), 256, 0, stream>>>(QKf, Vt, Oa, temp);

    gemm_bt<float><<<dim3(64, 8), 256, 0, stream>>>(Oa, WoT, (float*)d_out, 8192, 1024, 1024, 1024, 1024, 1024);
}

// Round 5
// 410.424 us; speedup vs baseline: 1.0089x; 1.0089x over previous
//
#include <hip/hip_runtime.h>

typedef unsigned short u16;
typedef unsigned int u32;
typedef __bf16 bf16x8 __attribute__((ext_vector_type(8)));
typedef float f32x4 __attribute__((ext_vector_type(4)));

#define DEV static __device__ __forceinline__

// async global->LDS, 16B per lane; dest is wave-uniform base + lane*16
DEV void gload16(const void* g, void* l) {
    __builtin_amdgcn_global_load_lds(
        (const __attribute__((address_space(1))) void*)g,
        (__attribute__((address_space(3))) void*)l, 16, 0, 0);
}

DEV void store_c(float* p, float v) { *p = v; }
DEV void store_c(u16* p, float v) { *(__bf16*)p = (__bf16)v; }

// swizzled LDS byte offset for 16B-granular tiles: XOR bits 4-6 with (row&7)
DEV int swz(int row, int bytecol) { return row * 128 + (bytecol ^ ((row & 7) << 4)); }
// Ps swizzle: additionally XOR bit 3 with row bit 3 -> conflict-free b64
// store/read (16 distinct bank-pairs per 16-lane quarter). 8B-aligned only.
DEV int swzP(int row, int bytecol) {
    return row * 128 + (bytecol ^ ((row & 7) << 4) ^ (row & 8));
}

// XCD chunked remap (T1): blocks with bid%8==j get a contiguous logical chunk.
// Requires nwg % 8 == 0 (bijective).
DEV void xcd_remap(int& bx, int& by, int gx, int gy) {
    int nwg = gx * gy;
    int bid = by * gx + bx;
    int logical = (bid & 7) * (nwg >> 3) + (bid >> 3);
    bx = logical % gx;
    by = logical / gx;
}

// ---------------------------------------------------------------------------
// pack zc = concat(z, connection) as bf16  [8192 x 2048]
// ---------------------------------------------------------------------------
__global__ void pack_zc(const float* __restrict__ z, const float* __restrict__ cn,
                        u16* __restrict__ zc) {
    size_t i = ((size_t)blockIdx.x * blockDim.x + threadIdx.x) * 4;
    size_t t = i >> 11;            // token
    int c = (int)(i & 2047);
    const float* src = (c < 1024) ? (z + t * 1024 + c) : (cn + t * 1024 + (c - 1024));
    float4 v = *reinterpret_cast<const float4*>(src);
    union { __bf16 h[4]; uint2 u; } o;
    o.h[0] = (__bf16)v.x; o.h[1] = (__bf16)v.y;
    o.h[2] = (__bf16)v.z; o.h[3] = (__bf16)v.w;
    *reinterpret_cast<uint2*>(zc + i) = o.u;
}

// ---------------------------------------------------------------------------
// W [K x N] fp32  ->  WT [N x K] bf16
// ---------------------------------------------------------------------------
__global__ void transpose_conv_w(const float* __restrict__ W, u16* __restrict__ WT,
                                 int K, int N) {
    __shared__ float tile[32][33];
    int n0 = blockIdx.x * 32, k0 = blockIdx.y * 32;
    int tx = threadIdx.x, ty = threadIdx.y;
    #pragma unroll
    for (int i = ty; i < 32; i += 8)
        tile[i][tx] = W[(size_t)(k0 + i) * N + n0 + tx];
    __syncthreads();
    #pragma unroll
    for (int i = ty; i < 32; i += 8)
        *(__bf16*)&WT[(size_t)(n0 + i) * K + k0 + tx] = (__bf16)tile[tx][i];
}

// ---------------------------------------------------------------------------
// Vflat [8192 x 1024] bf16 -> Vt [64(bh)][64(hd)][2048(L)] bf16
// ---------------------------------------------------------------------------
__global__ void transpose_v(const u16* __restrict__ Vf, u16* __restrict__ Vt) {
    __shared__ u16 tile[32][33];
    int bh = blockIdx.z; int b = bh >> 4, h = bh & 15;
    int l0 = blockIdx.x * 32, d0 = blockIdx.y * 32;
    int tx = threadIdx.x, ty = threadIdx.y;
    #pragma unroll
    for (int i = ty; i < 32; i += 8)
        tile[i][tx] = Vf[(size_t)(b * 2048 + l0 + i) * 1024 + h * 64 + d0 + tx];
    __syncthreads();
    #pragma unroll
    for (int i = ty; i < 32; i += 8)
        Vt[((size_t)bh * 64 + d0 + i) * 2048 + l0 + tx] = tile[tx][i];
}

// ---------------------------------------------------------------------------
// C[M x N] = A[M x K] @ BT[N x K]^T   (bf16 in, OutT out)
// 128x128 tile, BK=64, 4 waves, global_load_lds staging with pre-swizzled
// source (LDS[row][c] = global[row][c ^ (row&7)]), mfma_f32_16x16x32_bf16.
// XCD chunked remap for L2 locality (requires nwg % 8 == 0).
// ---------------------------------------------------------------------------
template <typename OutT>
__global__ __launch_bounds__(256, 2)
void gemm_bt(const u16* __restrict__ A, const u16* __restrict__ BT,
             OutT* __restrict__ C, int M, int N, int K,
             int lda, int ldb, int ldc) {
    __shared__ u16 As[128 * 64];
    __shared__ u16 Bs[128 * 64];
    const int tid = threadIdx.x;
    const int lane = tid & 63;
    const int wid = tid >> 6;
    int bx = blockIdx.x, by = blockIdx.y;
    xcd_remap(bx, by, gridDim.x, gridDim.y);
    const int m0 = bx * 128;
    const int n0 = by * 128;
    const int wr = (wid >> 1) * 64;
    const int wc = (wid & 1) * 64;

    f32x4 acc[4][4];
    #pragma unroll
    for (int i = 0; i < 4; ++i)
        #pragma unroll
        for (int j = 0; j < 4; ++j)
            acc[i][j] = f32x4{0.f, 0.f, 0.f, 0.f};

    // staging geometry: slot = (wid*4+p)*64 + lane; row = wid*32+p*8+(lane>>3)
    // row&7 == lane>>3, so source chunk = (lane&7) ^ (lane>>3) — lane constant.
    const int srcoff = ((lane & 7) ^ (lane >> 3)) * 8;   // elements
    const int rb = wid * 32 + (lane >> 3);
    const u16* aptr[4]; const u16* bptr[4];
    #pragma unroll
    for (int p = 0; p < 4; ++p) {
        aptr[p] = A  + (size_t)(m0 + rb + p * 8) * lda + srcoff;
        bptr[p] = BT + (size_t)(n0 + rb + p * 8) * ldb + srcoff;
    }

    for (int k0 = 0; k0 < K; k0 += 64) {
        __syncthreads();   // previous compute done before overwrite
        #pragma unroll
        for (int p = 0; p < 4; ++p)
            gload16(aptr[p] + k0, (char*)As + (wid * 4 + p) * 1024);
        #pragma unroll
        for (int p = 0; p < 4; ++p)
            gload16(bptr[p] + k0, (char*)Bs + (wid * 4 + p) * 1024);
        __syncthreads();   // staging complete (compiler drains vmcnt before barrier)

        #pragma unroll
        for (int kk = 0; kk < 64; kk += 32) {
            bf16x8 af[4], bfr[4];
            #pragma unroll
            for (int i = 0; i < 4; ++i) {
                int row = wr + i * 16 + (lane & 15);
                af[i] = *reinterpret_cast<const bf16x8*>(
                    reinterpret_cast<const char*>(As) + swz(row, (kk + (lane >> 4) * 8) * 2));
            }
            #pragma unroll
            for (int j = 0; j < 4; ++j) {
                int row = wc + j * 16 + (lane & 15);
                bfr[j] = *reinterpret_cast<const bf16x8*>(
                    reinterpret_cast<const char*>(Bs) + swz(row, (kk + (lane >> 4) * 8) * 2));
            }
            #pragma unroll
            for (int i = 0; i < 4; ++i)
                #pragma unroll
                for (int j = 0; j < 4; ++j)
                    acc[i][j] = __builtin_amdgcn_mfma_f32_16x16x32_bf16(af[i], bfr[j], acc[i][j], 0, 0, 0);
        }
    }

    #pragma unroll
    for (int i = 0; i < 4; ++i)
        #pragma unroll
        for (int j = 0; j < 4; ++j)
            #pragma unroll
            for (int r = 0; r < 4; ++r) {
                int row = m0 + wr + i * 16 + (lane >> 4) * 4 + r;
                int col = n0 + wc + j * 16 + (lane & 15);
                store_c(&C[(size_t)row * ldc + col], acc[i][j][r]);
            }
}

// ---------------------------------------------------------------------------
// Sigmoid attention: out[b,h,q,:] = (sigma(QK^T*scale) @ V) / max(rowsum,1)
// QKf [8192 x 2048]: cols 0-1023 Q, 1024-2047 K.
// grid (L/128, B*H) with XCD remap; 4 waves; each wave owns 32 q-rows.
// Q held in registers (4 b128/thread, loaded once). K/V double-buffered in
// LDS (T3-minimal: stage t+1, compute t, one barrier). SWAPPED QK^T:
// S = mfma(A=K, B=Q) -> lane holds 4 consecutive keys for one q -> packed
// b64 P-store into conflict-free swzP layout; PV A-frag = 2x ds_read_b64.
// rsum via MFMA against all-ones B (same C row mapping as oacc).
// ---------------------------------------------------------------------------
__global__ __launch_bounds__(256, 2)
void attn_kernel(const u16* __restrict__ QKf, const u16* __restrict__ Vt,
                 u16* __restrict__ Oa, const float* __restrict__ temp) {
    constexpr int L = 2048, D = 1024, QKLD = 2048, HD = 64;
    __shared__ u16 Ks[2][64 * 64];
    __shared__ u16 Vs[2][64 * 64];
    __shared__ u16 Ps[4][32 * 64];   // per-wave P tile [32 q][64 keys], swzP

    const int tid = threadIdx.x;
    const int lane = tid & 63;
    const int wid = tid >> 6;
    const int hi = lane >> 4;
    int bx = blockIdx.x, by = blockIdx.y;
    xcd_remap(bx, by, gridDim.x, gridDim.y);   // nwg = 1024
    const int bh = by;
    const int b = bh >> 4, h = bh & 15;
    const int q0 = bx * 128;
    const float sneg = -temp[0] * 0.125f * 1.44269504f;   // exp2-domain scale

    const u16* Qbase = QKf + (size_t)(b * L) * QKLD + h * HD;
    const u16* Kbase = Qbase + 1024;
    const u16* Vbase = Vt + (size_t)bh * HD * L;

    // staging geometry: one gload16 covers 8 LDS rows; row&7 == lane>>3,
    // so pre-swizzled source chunk = (lane&7) ^ (lane>>3) — lane constant.
    const int srcoff = ((lane & 7) ^ (lane >> 3)) * 8;
    const int rb = wid * 16 + (lane >> 3);
    const u16* kptr[2]; const u16* vptr[2];
    #pragma unroll
    for (int p = 0; p < 2; ++p) {
        kptr[p] = Kbase + (size_t)(rb + p * 8) * QKLD + srcoff;
        vptr[p] = Vbase + (size_t)(rb + p * 8) * L + srcoff;
    }

    // Q fragments -> registers (replaces Qs LDS tile entirely)
    bf16x8 qf[2][2];
    #pragma unroll
    for (int i = 0; i < 2; ++i)
        #pragma unroll
        for (int kx = 0; kx < 2; ++kx)
            qf[i][kx] = *reinterpret_cast<const bf16x8*>(
                Qbase + (size_t)(q0 + wid * 32 + i * 16 + (lane & 15)) * QKLD + kx * 32 + hi * 8);

    // prologue: stage tile 0 into buffer 0
    #pragma unroll
    for (int p = 0; p < 2; ++p)
        gload16(kptr[p], (char*)Ks[0] + (wid * 2 + p) * 1024);
    #pragma unroll
    for (int p = 0; p < 2; ++p)
        gload16(vptr[p], (char*)Vs[0] + (wid * 2 + p) * 1024);

    bf16x8 onesf;
    #pragma unroll
    for (int j = 0; j < 8; ++j) onesf[j] = (__bf16)1.0f;

    f32x4 oacc[4][2];
    #pragma unroll
    for (int ct = 0; ct < 4; ++ct)
        #pragma unroll
        for (int i = 0; i < 2; ++i) oacc[ct][i] = f32x4{0.f, 0.f, 0.f, 0.f};
    f32x4 racc[2];
    racc[0] = f32x4{0.f, 0.f, 0.f, 0.f};
    racc[1] = f32x4{0.f, 0.f, 0.f, 0.f};

    __syncthreads();   // prologue staging drained (vmcnt(0) before barrier)
    int cur = 0;

    for (int k0 = 0; k0 < L; k0 += 64) {
        // issue next tile's staging early — latency hides under compute
        if (k0 + 64 < L) {
            #pragma unroll
            for (int p = 0; p < 2; ++p)
                gload16(kptr[p] + (size_t)(k0 + 64) * QKLD, (char*)Ks[cur ^ 1] + (wid * 2 + p) * 1024);
            #pragma unroll
            for (int p = 0; p < 2; ++p)
                gload16(vptr[p] + (k0 + 64), (char*)Vs[cur ^ 1] + (wid * 2 + p) * 1024);
        }

        // S[key][q] = mfma(A=K, B=Q): lane holds q=lane&15 (per subtile),
        // keys = ct*16 + hi*4 + r
        f32x4 s[4][2];
        #pragma unroll
        for (int ct = 0; ct < 4; ++ct)
            #pragma unroll
            for (int i = 0; i < 2; ++i) s[ct][i] = f32x4{0.f, 0.f, 0.f, 0.f};
        #pragma unroll
        for (int kx = 0; kx < 2; ++kx) {
            bf16x8 ak[4];
            #pragma unroll
            for (int ct = 0; ct < 4; ++ct) {
                int krow = ct * 16 + (lane & 15);
                ak[ct] = *reinterpret_cast<const bf16x8*>(
                    reinterpret_cast<const char*>(Ks[cur]) + swz(krow, kx * 64 + hi * 16));
            }
            #pragma unroll
            for (int ct = 0; ct < 4; ++ct)
                #pragma unroll
                for (int i = 0; i < 2; ++i)
                    s[ct][i] = __builtin_amdgcn_mfma_f32_16x16x32_bf16(ak[ct], qf[i][kx], s[ct][i], 0, 0, 0);
        }

        // sigmoid -> packed b64 P-store (conflict-free swzP layout)
        #pragma unroll
        for (int i = 0; i < 2; ++i) {
            int prow = i * 16 + (lane & 15);
            #pragma unroll
            for (int ct = 0; ct < 4; ++ct) {
                union { __bf16 hh[4]; uint2 uu; } pk;
                #pragma unroll
                for (int r = 0; r < 4; ++r)
                    pk.hh[r] = (__bf16)__builtin_amdgcn_rcpf(1.0f + exp2f(s[ct][i][r] * sneg));
                *reinterpret_cast<uint2*>(reinterpret_cast<char*>(Ps[wid]) +
                    swzP(prow, ct * 32 + hi * 8)) = pk.uu;
            }
        }
        // no barrier: Ps is per-wave (same-wave DS ops are in-order)

        // O += P @ V ; rsum += P @ ones (matrix pipe)
        #pragma unroll
        for (int kx = 0; kx < 2; ++kx) {
            bf16x8 ap[2];
            #pragma unroll
            for (int i = 0; i < 2; ++i) {
                int prow = i * 16 + (lane & 15);
                union { u32 w[4]; bf16x8 v; } apu;
                *reinterpret_cast<uint2*>(&apu.w[0]) = *reinterpret_cast<const uint2*>(
                    reinterpret_cast<const char*>(Ps[wid]) + swzP(prow, kx * 64 + hi * 16));
                *reinterpret_cast<uint2*>(&apu.w[2]) = *reinterpret_cast<const uint2*>(
                    reinterpret_cast<const char*>(Ps[wid]) + swzP(prow, kx * 64 + hi * 16 + 8));
                ap[i] = apu.v;
            }
            racc[0] = __builtin_amdgcn_mfma_f32_16x16x32_bf16(ap[0], onesf, racc[0], 0, 0, 0);
            racc[1] = __builtin_amdgcn_mfma_f32_16x16x32_bf16(ap[1], onesf, racc[1], 0, 0, 0);
            #pragma unroll
            for (int ct = 0; ct < 4; ++ct) {
                int vrow = ct * 16 + (lane & 15);   // output channel c
                bf16x8 bv = *reinterpret_cast<const bf16x8*>(
                    reinterpret_cast<const char*>(Vs[cur]) + swz(vrow, kx * 64 + hi * 16));
                #pragma unroll
                for (int i = 0; i < 2; ++i)
                    oacc[ct][i] = __builtin_amdgcn_mfma_f32_16x16x32_bf16(ap[i], bv, oacc[ct][i], 0, 0, 0);
            }
        }

        __syncthreads();   // next tile arrived (vmcnt drain) + all done with cur
        cur ^= 1;
    }

    float rdiv[2][4];
    #pragma unroll
    for (int i = 0; i < 2; ++i)
        #pragma unroll
        for (int r = 0; r < 4; ++r)
            rdiv[i][r] = __builtin_amdgcn_rcpf(fmaxf(racc[i][r], 1.0f));

    #pragma unroll
    for (int ct = 0; ct < 4; ++ct)
        #pragma unroll
        for (int i = 0; i < 2; ++i)
            #pragma unroll
            for (int r = 0; r < 4; ++r) {
                int row = q0 + wid * 32 + i * 16 + hi * 4 + r;
                int col = h * HD + ct * 16 + (lane & 15);
                *(__bf16*)&Oa[(size_t)(b * L + row) * D + col] =
                    (__bf16)(oacc[ct][i][r] * rdiv[i][r]);
            }
}

// ---------------------------------------------------------------------------
extern "C" void kernel_launch(void* const* d_in, const int* in_sizes, int n_in,
                              void* d_out, int out_size, void* d_ws, size_t ws_size,
                              hipStream_t stream) {
    const float* z    = (const float*)d_in[0];
    const float* cn   = (const float*)d_in[1];
    const float* Wq   = (const float*)d_in[2];
    const float* Wk   = (const float*)d_in[3];
    const float* Wv   = (const float*)d_in[4];
    const float* Wo   = (const float*)d_in[5];
    const float* temp = (const float*)d_in[6];

    // Workspace layout (92 MB total):
    //   WqT/WkT contiguous (merged QK GEMM reads them as one [2048][2048] BT).
    //   zc dead after projections -> Vt aliases zc.
    //   Vf dead after transpose_v -> Oa aliases Vf.
    char* ws = (char*)d_ws;
    u16* zc  = (u16*)ws; ws += (size_t)8192 * 2048 * 2;   // 32 MB
    u16* WqT = (u16*)ws; ws += (size_t)1024 * 2048 * 2;   //  4 MB
    u16* WkT = (u16*)ws; ws += (size_t)1024 * 2048 * 2;   //  4 MB (contiguous after WqT)
    u16* WvT = (u16*)ws; ws += (size_t)1024 * 1024 * 2;   //  2 MB
    u16* WoT = (u16*)ws; ws += (size_t)1024 * 1024 * 2;   //  2 MB
    u16* QKf = (u16*)ws; ws += (size_t)8192 * 2048 * 2;   // 32 MB (Q cols 0-1023, K cols 1024-2047)
    u16* Vf  = (u16*)ws; ws += (size_t)8192 * 1024 * 2;   // 16 MB
    u16* Vt  = zc;   // alias: zc dead after projections
    u16* Oa  = Vf;   // alias: Vf dead after transpose_v

    pack_zc<<<16384, 256, 0, stream>>>(z, cn, zc);

    dim3 tb(32, 8);
    transpose_conv_w<<<dim3(32, 64), tb, 0, stream>>>(Wq, WqT, 2048, 1024);
    transpose_conv_w<<<dim3(32, 64), tb, 0, stream>>>(Wk, WkT, 2048, 1024);
    transpose_conv_w<<<dim3(32, 32), tb, 0, stream>>>(Wv, WvT, 1024, 1024);
    transpose_conv_w<<<dim3(32, 32), tb, 0, stream>>>(Wo, WoT, 1024, 1024);

    // merged Q+K projection: [8192,2048] @ [2048,2048]^T -> QKf
    gemm_bt<u16><<<dim3(64, 16), 256, 0, stream>>>(zc, WqT, QKf, 8192, 2048, 2048, 2048, 2048, 2048);
    gemm_bt<u16><<<dim3(64, 8),  256, 0, stream>>>(zc, WvT, Vf,  8192, 1024, 1024, 2048, 1024, 1024);

    transpose_v<<<dim3(64, 2, 64), tb, 0, stream>>>(Vf, Vt);

    attn_kernel<<<dim3(16, 64), 256, 0, stream>>>(QKf, Vt, Oa, temp);

    gemm_bt<float><<<dim3(64, 8), 256, 0, stream>>>(Oa, WoT, (float*)d_out, 8192, 1024, 1024, 1024, 1024, 1024);
}